// Round 2
// baseline (271.200 us; speedup 1.0000x reference)
//
#include <hip/hip_runtime.h>

#define HH 1024
#define WW 1024
#define TSX 128            // tile width in pixels
#define TILE_H 64          // tile height in pixels; 4 waves x 16 rows each
#define ROWS_PW 16
#define SMW 134            // (TSX+4)=132 used, +2 pad -> even stride, 8B-aligned float2 reads
#define SMH (TILE_H + 4)   // 68
#define EPSF 1e-8f

__device__ __forceinline__ float rcpf(float x) { return __builtin_amdgcn_rcpf(x); }

__global__ __launch_bounds__(256) void demosaick(
    const float* __restrict__ mos,
    const float* __restrict__ gfilt,
    const float* __restrict__ gradf,
    float* __restrict__ out)
{
    __shared__ __align__(16) float SM[SMH * SMW];   // 36448 B
    const int tid  = threadIdx.x;
    const int lane = tid & 63;          // column-pair owner within a wave
    const int wv   = tid >> 6;          // wave id -> row group
    const int bx = blockIdx.x, by = blockIdx.y, bz = blockIdx.z;
    const int gx0 = bx * TSX;
    const int gy0 = by * TILE_H;
    const size_t plane = (size_t)HH * WW;
    const float* __restrict__ src = mos + (size_t)bz * plane;

    const float gf0 = gfilt[0], gf1 = gfilt[1], gf2 = gfilt[2];
    const float df0 = gradf[0], df1 = gradf[1], df2 = gradf[2];

    // Stage m tile (halo 2), edge-clamped => corr1d edge padding for free.
    for (int i = tid; i < SMH * (TSX + 4); i += 256) {
        int r = i / (TSX + 4);
        int c = i - r * (TSX + 4);
        int gy = min(max(gy0 - 2 + r, 0), HH - 1);
        int gx = min(max(gx0 - 2 + c, 0), WW - 1);
        SM[r * SMW + c] = src[(size_t)gy * WW + gx];
    }
    __syncthreads();

    const int ry0 = gy0 + wv * ROWS_PW;      // first output row for this wave
    const int sr0 = wv * ROWS_PW;            // SM row holding m(ry0 - 2)

    // Per-thread column window: M cols map to global x0-2 .. x0+3 (x0 = gx0+2*lane, even)
    auto load_row = [&](int smr, float* d) {
        const float2* p = reinterpret_cast<const float2*>(&SM[smr * SMW + 2 * lane]);
        float2 a = p[0], b2 = p[1], c2 = p[2];
        d[0] = a.x; d[1] = a.y; d[2] = b2.x; d[3] = b2.y; d[4] = c2.x; d[5] = c2.y;
    };
    auto gi_at = [&](const float* up, const float* mid, const float* dn, int j) -> float {
        float xl = mid[j - 1], xc = mid[j], xr = mid[j + 1];
        float yu = up[j], yd = dn[j];
        float dx = df0 * xl + df1 * xc + df2 * xr;
        float dy = df0 * yu + df1 * xc + df2 * yd;
        float gh = gf0 * xl + gf1 * xc + gf2 * xr;
        float gv = gf0 * yu + gf1 * xc + gf2 * yd;
        float adx = fabsf(dx), ady = fabsf(dy);
        float w = ady * rcpf(adx + ady + EPSF);
        return w * gh + (1.0f - w) * gv;
    };
    // G cols map to global x0-1 .. x0+2 (G[k] <-> M[k+1])
    auto green_row = [&](int gy, const float* up, const float* mid, const float* dn, float* G) {
        if (gy & 1) {   // odd row: green at odd x -> G[0],G[2]; interpolate G[1],G[3]
            G[0] = mid[1]; G[2] = mid[3];
            G[1] = gi_at(up, mid, dn, 2);
            G[3] = gi_at(up, mid, dn, 4);
        } else {        // even row: green at even x -> G[1],G[3]; interpolate G[0],G[2]
            G[1] = mid[2]; G[3] = mid[4];
            G[0] = gi_at(up, mid, dn, 1);
            G[2] = gi_at(up, mid, dn, 3);
        }
    };

    float A[6], Mm1[6], M0[6], Mp1[6], Mp2[6];
    float Gm1[4], G0[4], Gp1[4];
    load_row(sr0 + 0, A);      // m(ry0-2)
    load_row(sr0 + 1, Mm1);    // m(ry0-1)
    load_row(sr0 + 2, M0);     // m(ry0)
    load_row(sr0 + 3, Mp1);    // m(ry0+1)
    green_row(ry0 - 1, A, Mm1, M0, Gm1);
    green_row(ry0,     Mm1, M0, Mp1, G0);

    const int x0 = gx0 + 2 * lane;
    const float wL = (x0 - 1 >= 0) ? 1.0f : 0.0f;   // x0-1 in image
    const float wR = (x0 + 2 < WW) ? 1.0f : 0.0f;   // x0+2 in image
    float* __restrict__ obase = out + (size_t)bz * 3 * plane + (size_t)x0;

    #pragma unroll 4
    for (int r = 0; r < ROWS_PW; ++r) {
        const int y = ry0 + r;
        load_row(sr0 + r + 4, Mp2);                 // m(y+2)
        green_row(y + 1, M0, Mp1, Mp2, Gp1);        // green(y+1)

        const float fU = (y > 0) ? 1.0f : 0.0f;
        const float fD = (y < HH - 1) ? 1.0f : 0.0f;
        const float g0 = G0[1], g1 = G0[2];
        const float m0 = M0[2], m1 = M0[3];
        float r0, b0, r1, b1;
        if ((y & 1) == 0) {
            // pixel0 (even,even): green site. R from horizontal pair, B from vertical pair.
            {
                float dL = M0[1] - G0[0], dR = M0[3] - G0[2];
                r0 = g0 + (0.5f * (wL * dL + dR)) * rcpf(0.5f * (wL + 1.0f) + EPSF);
                float dU = Mm1[2] - Gm1[1], dD = Mp1[2] - Gp1[1];
                b0 = g0 + (0.5f * (fU * dU + fD * dD)) * rcpf(0.5f * (fU + fD) + EPSF);
            }
            // pixel1 (even,odd): R site. red = m; B from 4 corners.
            {
                r1 = m1;
                float dUL = Mm1[2] - Gm1[1], dUR = Mm1[4] - Gm1[3];
                float dDL = Mp1[2] - Gp1[1], dDR = Mp1[4] - Gp1[3];
                float num = 0.25f * (fU * (dUL + wR * dUR) + fD * (dDL + wR * dDR));
                float den = 0.25f * ((fU + fD) * (1.0f + wR));
                b1 = g1 + num * rcpf(den + EPSF);
            }
        } else {
            // pixel0 (odd,even): B site. blue = m; R from 4 corners.
            {
                b0 = m0;
                float dUL = Mm1[1] - Gm1[0], dUR = Mm1[3] - Gm1[2];
                float dDL = Mp1[1] - Gp1[0], dDR = Mp1[3] - Gp1[2];
                float num = 0.25f * (fU * (wL * dUL + dUR) + fD * (wL * dDL + dDR));
                float den = 0.25f * ((fU + fD) * (wL + 1.0f));
                r0 = g0 + num * rcpf(den + EPSF);
            }
            // pixel1 (odd,odd): green site. R from vertical pair, B from horizontal pair.
            {
                float dU = Mm1[3] - Gm1[2], dD = Mp1[3] - Gp1[2];
                r1 = g1 + (0.5f * (fU * dU + fD * dD)) * rcpf(0.5f * (fU + fD) + EPSF);
                float dL = M0[2] - G0[1], dR = M0[4] - G0[3];
                b1 = g1 + (0.5f * (dL + wR * dR)) * rcpf(0.5f * (1.0f + wR) + EPSF);
            }
        }

        float* prow = obase + (size_t)y * WW;
        *reinterpret_cast<float2*>(prow)             = make_float2(r0, r1);   // red
        *reinterpret_cast<float2*>(prow + plane)     = make_float2(g0, g1);   // green
        *reinterpret_cast<float2*>(prow + 2 * plane) = make_float2(b0, b1);   // blue

        #pragma unroll
        for (int j = 0; j < 6; ++j) { Mm1[j] = M0[j]; M0[j] = Mp1[j]; Mp1[j] = Mp2[j]; }
        #pragma unroll
        for (int j = 0; j < 4; ++j) { Gm1[j] = G0[j]; G0[j] = Gp1[j]; }
    }
}

extern "C" void kernel_launch(void* const* d_in, const int* in_sizes, int n_in,
                              void* d_out, int out_size, void* d_ws, size_t ws_size,
                              hipStream_t stream) {
    const float* mos = (const float*)d_in[0];
    const float* gf  = (const float*)d_in[1];
    const float* df  = (const float*)d_in[2];
    float* o = (float*)d_out;
    int B = in_sizes[0] / (HH * WW);
    dim3 grid(WW / TSX, HH / TILE_H, B);
    demosaick<<<grid, dim3(256, 1, 1), 0, stream>>>(mos, gf, df, o);
}

// Round 3
// 261.937 us; speedup vs baseline: 1.0354x; 1.0354x over previous
//
#include <hip/hip_runtime.h>

#define HH 1024
#define WW 1024
#define ROWS 16            // rows per thread; grid.y = HH/ROWS
#define EPSF 1e-8f

__device__ __forceinline__ float rcpf(float x) { return __builtin_amdgcn_rcpf(x); }

__global__ __launch_bounds__(256, 4) void demosaick(
    const float* __restrict__ mos,
    const float* __restrict__ gfilt,
    const float* __restrict__ gradf,
    float* __restrict__ out)
{
    const int tid = threadIdx.x;
    const int x0  = tid * 4;                  // 256 threads x 4 cols = full 1024-wide row band
    const int by = blockIdx.y, bz = blockIdx.z;
    const int ry0 = by * ROWS;
    const size_t plane = (size_t)HH * WW;
    const float* __restrict__ src = mos + (size_t)bz * plane;

    const float gf0 = gfilt[0], gf1 = gfilt[1], gf2 = gfilt[2];
    const float df0 = gradf[0], df1 = gradf[1], df2 = gradf[2];

    const bool eL = (x0 == 0);
    const bool eR = (x0 == WW - 4);
    const int bLc = eL ? 0 : x0 - 2;          // clamped, 8B-aligned
    const int bRc = eR ? WW - 2 : x0 + 4;

    // Window w[0..7] = m[y, x0-2 .. x0+5], edge-replicated in x (pad=1 semantics).
    auto load_mrow = [&](int y, float* w) {
        int yy = min(max(y, 0), HH - 1);      // edge-pad in y for corr1d
        const float* row = src + (size_t)yy * WW;
        float4 q1 = *reinterpret_cast<const float4*>(row + x0);
        float2 q0 = *reinterpret_cast<const float2*>(row + bLc);
        float2 q2 = *reinterpret_cast<const float2*>(row + bRc);
        w[2] = q1.x; w[3] = q1.y; w[4] = q1.z; w[5] = q1.w;
        w[0] = eL ? q1.x : q0.x;              // m[-2]->m[0] (masked use), m[-1]->m[0] (edge pad)
        w[1] = eL ? q1.x : q0.y;
        w[6] = eR ? q2.y : q2.x;              // m[W]->m[W-1] (edge pad)
        w[7] = q2.y;                          // m[W+1] only feeds masked green
    };

    auto gi_at = [&](const float* up, const float* mid, const float* dn, int j) -> float {
        float xl = mid[j - 1], xc = mid[j], xr = mid[j + 1];
        float yu = up[j], yd = dn[j];
        float dx = df0 * xl + df1 * xc + df2 * xr;
        float dy = df0 * yu + df1 * xc + df2 * yd;
        float gh = gf0 * xl + gf1 * xc + gf2 * xr;
        float gv = gf0 * yu + gf1 * xc + gf2 * yd;
        float adx = fabsf(dx), ady = fabsf(dy);
        float w = ady * rcpf(adx + ady + EPSF);
        return w * gh + (1.0f - w) * gv;
    };
    // G[g] <-> col x0-1+g (g=0..5); window idx j = g+1.
    auto green_row = [&](int y, const float* up, const float* mid, const float* dn, float* G) {
        if (y & 1) {       // odd row: green at odd cols -> g even copies
            G[0] = mid[1]; G[2] = mid[3]; G[4] = mid[5];
            G[1] = gi_at(up, mid, dn, 2);
            G[3] = gi_at(up, mid, dn, 4);
            G[5] = gi_at(up, mid, dn, 6);
        } else {           // even row: green at even cols -> g odd copies
            G[1] = mid[2]; G[3] = mid[4]; G[5] = mid[6];
            G[0] = gi_at(up, mid, dn, 1);
            G[2] = gi_at(up, mid, dn, 3);
            G[4] = gi_at(up, mid, dn, 5);
        }
    };

    float A8[8], Mm1[8], M0[8], Mp1[8], Mp2[8];
    float Gm1[6], G0[6], Gp1[6];
    load_mrow(ry0 - 2, A8);
    load_mrow(ry0 - 1, Mm1);
    load_mrow(ry0,     M0);
    load_mrow(ry0 + 1, Mp1);
    green_row(ry0 - 1, A8, Mm1, M0, Gm1);
    green_row(ry0,     Mm1, M0, Mp1, G0);

    const float wl0 = eL ? 0.0f : 1.0f;       // col x0-1 in image? (only p=0 can fail)
    const float wr3 = eR ? 0.0f : 1.0f;       // col x0+4 in image? (only p=3 can fail)
    float* __restrict__ obase = out + (size_t)bz * 3 * plane + (size_t)x0;

    #pragma unroll 4
    for (int r = 0; r < ROWS; ++r) {
        const int y = ry0 + r;
        load_mrow(y + 2, Mp2);
        green_row(y + 1, M0, Mp1, Mp2, Gp1);

        const float fU = (y > 0) ? 1.0f : 0.0f;
        const float fD = (y < HH - 1) ? 1.0f : 0.0f;

        auto wl = [&](int p) -> float { return p == 0 ? wl0 : 1.0f; };
        auto wr = [&](int p) -> float { return p == 3 ? wr3 : 1.0f; };
        auto pair_h = [&](int p) -> float {   // horizontal neighbor pair at (y, x0+p)
            float dL = M0[p + 1] - G0[p], dR = M0[p + 3] - G0[p + 2];
            float num = wl(p) * dL + wr(p) * dR;
            float den = wl(p) + wr(p);
            return G0[p + 1] + (0.5f * num) * rcpf(0.5f * den + EPSF);
        };
        auto pair_v = [&](int p) -> float {   // vertical neighbor pair
            float dU = Mm1[p + 2] - Gm1[p + 1], dD = Mp1[p + 2] - Gp1[p + 1];
            return G0[p + 1] + (0.5f * (fU * dU + fD * dD)) * rcpf(0.5f * (fU + fD) + EPSF);
        };
        auto corners = [&](int p) -> float {  // 4 diagonal neighbors
            float dUL = Mm1[p + 1] - Gm1[p],     dUR = Mm1[p + 3] - Gm1[p + 2];
            float dDL = Mp1[p + 1] - Gp1[p],     dDR = Mp1[p + 3] - Gp1[p + 2];
            float num = 0.25f * (fU * (wl(p) * dUL + wr(p) * dUR) + fD * (wl(p) * dDL + wr(p) * dDR));
            float den = 0.25f * ((fU + fD) * (wl(p) + wr(p)));
            return G0[p + 1] + num * rcpf(den + EPSF);
        };

        float R[4], Bv[4];
        if ((y & 1) == 0) {
            // even row: p even = green site (R horiz, B vert); p odd = R site (B corners)
            R[0] = pair_h(0);  Bv[0] = pair_v(0);
            R[1] = M0[3];      Bv[1] = corners(1);
            R[2] = pair_h(2);  Bv[2] = pair_v(2);
            R[3] = M0[5];      Bv[3] = corners(3);
        } else {
            // odd row: p even = B site (R corners); p odd = green site (R vert, B horiz)
            R[0] = corners(0); Bv[0] = M0[2];
            R[1] = pair_v(1);  Bv[1] = pair_h(1);
            R[2] = corners(2); Bv[2] = M0[4];
            R[3] = pair_v(3);  Bv[3] = pair_h(3);
        }

        float* prow = obase + (size_t)y * WW;
        *reinterpret_cast<float4*>(prow)             = make_float4(R[0], R[1], R[2], R[3]);
        *reinterpret_cast<float4*>(prow + plane)     = make_float4(G0[1], G0[2], G0[3], G0[4]);
        *reinterpret_cast<float4*>(prow + 2 * plane) = make_float4(Bv[0], Bv[1], Bv[2], Bv[3]);

        #pragma unroll
        for (int j = 0; j < 8; ++j) { Mm1[j] = M0[j]; M0[j] = Mp1[j]; Mp1[j] = Mp2[j]; }
        #pragma unroll
        for (int j = 0; j < 6; ++j) { Gm1[j] = G0[j]; G0[j] = Gp1[j]; }
    }
}

extern "C" void kernel_launch(void* const* d_in, const int* in_sizes, int n_in,
                              void* d_out, int out_size, void* d_ws, size_t ws_size,
                              hipStream_t stream) {
    const float* mos = (const float*)d_in[0];
    const float* gf  = (const float*)d_in[1];
    const float* df  = (const float*)d_in[2];
    float* o = (float*)d_out;
    int B = in_sizes[0] / (HH * WW);
    dim3 grid(1, HH / ROWS, B);
    demosaick<<<grid, dim3(256, 1, 1), 0, stream>>>(mos, gf, df, o);
}

// Round 5
// 259.423 us; speedup vs baseline: 1.0454x; 1.0097x over previous
//
#include <hip/hip_runtime.h>

#define HH 1024
#define WW 1024
#define ROWS 16            // rows per thread; grid.y = HH/ROWS
#define EPSF 1e-8f

typedef float vfloat4 __attribute__((ext_vector_type(4)));

__device__ __forceinline__ float rcpf(float x) { return __builtin_amdgcn_rcpf(x); }
__device__ __forceinline__ void ntstore4(float* p, float a, float b, float c, float d) {
    vfloat4 v = {a, b, c, d};
    __builtin_nontemporal_store(v, reinterpret_cast<vfloat4*>(p));
}

__global__ __launch_bounds__(256, 4) void demosaick(
    const float* __restrict__ mos,
    const float* __restrict__ gfilt,
    const float* __restrict__ gradf,
    float* __restrict__ out)
{
    const int tid = threadIdx.x;
    const int x0  = tid * 4;                  // 256 threads x 4 cols = full 1024-wide row band
    const int by = blockIdx.y, bz = blockIdx.z;
    const int ry0 = by * ROWS;
    const size_t plane = (size_t)HH * WW;
    const float* __restrict__ src = mos + (size_t)bz * plane;

    const float gf0 = gfilt[0], gf1 = gfilt[1], gf2 = gfilt[2];
    const float df0 = gradf[0], df1 = gradf[1], df2 = gradf[2];

    const bool eL = (x0 == 0);
    const bool eR = (x0 == WW - 4);
    const int bLc = eL ? 0 : x0 - 2;          // clamped, 8B-aligned
    const int bRc = eR ? WW - 2 : x0 + 4;

    // Window w[0..7] = m[y, x0-2 .. x0+5], edge-replicated in x (pad=1 semantics).
    auto load_mrow = [&](int y, float* w) {
        int yy = min(max(y, 0), HH - 1);      // edge-pad in y for corr1d
        const float* row = src + (size_t)yy * WW;
        float4 q1 = *reinterpret_cast<const float4*>(row + x0);
        float2 q0 = *reinterpret_cast<const float2*>(row + bLc);
        float2 q2 = *reinterpret_cast<const float2*>(row + bRc);
        w[2] = q1.x; w[3] = q1.y; w[4] = q1.z; w[5] = q1.w;
        w[0] = eL ? q1.x : q0.x;
        w[1] = eL ? q1.x : q0.y;
        w[6] = eR ? q2.y : q2.x;
        w[7] = q2.y;
    };

    auto gi_at = [&](const float* up, const float* mid, const float* dn, int j) -> float {
        float xl = mid[j - 1], xc = mid[j], xr = mid[j + 1];
        float yu = up[j], yd = dn[j];
        float dx = df0 * xl + df1 * xc + df2 * xr;
        float dy = df0 * yu + df1 * xc + df2 * yd;
        float gh = gf0 * xl + gf1 * xc + gf2 * xr;
        float gv = gf0 * yu + gf1 * xc + gf2 * yd;
        float adx = fabsf(dx), ady = fabsf(dy);
        float w = ady * rcpf(adx + ady + EPSF);
        return w * gh + (1.0f - w) * gv;
    };
    // G[g] <-> col x0-1+g (g=0..5); window idx j = g+1.
    auto green_row = [&](int y, const float* up, const float* mid, const float* dn, float* G) {
        if (y & 1) {
            G[0] = mid[1]; G[2] = mid[3]; G[4] = mid[5];
            G[1] = gi_at(up, mid, dn, 2);
            G[3] = gi_at(up, mid, dn, 4);
            G[5] = gi_at(up, mid, dn, 6);
        } else {
            G[1] = mid[2]; G[3] = mid[4]; G[5] = mid[6];
            G[0] = gi_at(up, mid, dn, 1);
            G[2] = gi_at(up, mid, dn, 3);
            G[4] = gi_at(up, mid, dn, 5);
        }
    };

    float A8[8], Mm1[8], M0[8], Mp1[8], Mp2[8];
    float Gm1[6], G0[6], Gp1[6];
    load_mrow(ry0 - 2, A8);
    load_mrow(ry0 - 1, Mm1);
    load_mrow(ry0,     M0);
    load_mrow(ry0 + 1, Mp1);
    green_row(ry0 - 1, A8, Mm1, M0, Gm1);
    green_row(ry0,     Mm1, M0, Mp1, G0);

    const float wl0 = eL ? 0.0f : 1.0f;       // col x0-1 in image? (only p=0 can fail)
    const float wr3 = eR ? 0.0f : 1.0f;       // col x0+4 in image? (only p=3 can fail)
    // Loop-invariant reciprocals. Interior denominators are exactly 1.0f in fp32
    // (1.0+1e-8 and 0.5+1e-8 both round to the unperturbed value), so these are
    // 0.5/0.25 for interior lanes and 1.0/0.5 for the two edge lanes.
    const float invL = rcpf(0.5f * (wl0 + 1.0f) + EPSF);
    const float invR = rcpf(0.5f * (1.0f + wr3) + EPSF);
    const float halfL = 0.5f * invL, quarterL = 0.25f * invL;
    const float halfR = 0.5f * invR, quarterR = 0.25f * invR;

    float* __restrict__ obase = out + (size_t)bz * 3 * plane + (size_t)x0;

    #pragma unroll 4
    for (int r = 0; r < ROWS; ++r) {
        const int y = ry0 + r;
        load_mrow(y + 2, Mp2);
        green_row(y + 1, M0, Mp1, Mp2, Gp1);

        const float g0 = G0[1], g1 = G0[2], g2 = G0[3], g3 = G0[4];
        float R[4], Bv[4];

        if (__builtin_expect(y > 0 && y < HH - 1, 1)) {
            // -------- interior rows: all vertical/corner dens == 1 exactly --------
            if ((y & 1) == 0) {
                float dU0 = Mm1[2] - Gm1[1], dD0 = Mp1[2] - Gp1[1];
                float dU2 = Mm1[4] - Gm1[3], dD2 = Mp1[4] - Gp1[3];
                R[0]  = g0 + halfL * (wl0 * (M0[1] - G0[0]) + (M0[3] - G0[2]));
                Bv[0] = g0 + 0.5f * (dU0 + dD0);
                R[1]  = M0[3];
                Bv[1] = g1 + 0.25f * (dU0 + dU2 + dD0 + dD2);
                R[2]  = g2 + 0.5f * ((M0[3] - G0[2]) + (M0[5] - G0[4]));
                Bv[2] = g2 + 0.5f * (dU2 + dD2);
                R[3]  = M0[5];
                Bv[3] = g3 + quarterR * ((dU2 + dD2) + wr3 * ((Mm1[6] - Gm1[5]) + (Mp1[6] - Gp1[5])));
            } else {
                float dU1 = Mm1[3] - Gm1[2], dD1 = Mp1[3] - Gp1[2];
                float dU3 = Mm1[5] - Gm1[4], dD3 = Mp1[5] - Gp1[4];
                Bv[0] = M0[2];
                R[0]  = g0 + quarterL * (wl0 * ((Mm1[1] - Gm1[0]) + (Mp1[1] - Gp1[0])) + (dU1 + dD1));
                R[1]  = g1 + 0.5f * (dU1 + dD1);
                Bv[1] = g1 + 0.5f * ((M0[2] - G0[1]) + (M0[4] - G0[3]));
                Bv[2] = M0[4];
                R[2]  = g2 + 0.25f * (dU1 + dU3 + dD1 + dD3);
                R[3]  = g3 + 0.5f * (dU3 + dD3);
                Bv[3] = g3 + halfR * ((M0[4] - G0[3]) + wr3 * (M0[6] - G0[5]));
            }
        } else {
            // -------- border rows y==0 / y==HH-1: general masked path --------
            const float fU = (y > 0) ? 1.0f : 0.0f;
            const float fD = (y < HH - 1) ? 1.0f : 0.0f;
            auto wl = [&](int p) -> float { return p == 0 ? wl0 : 1.0f; };
            auto wr = [&](int p) -> float { return p == 3 ? wr3 : 1.0f; };
            auto pair_h = [&](int p) -> float {
                float dL = M0[p + 1] - G0[p], dR = M0[p + 3] - G0[p + 2];
                return G0[p + 1] + (0.5f * (wl(p) * dL + wr(p) * dR)) * rcpf(0.5f * (wl(p) + wr(p)) + EPSF);
            };
            auto pair_v = [&](int p) -> float {
                float dU = Mm1[p + 2] - Gm1[p + 1], dD = Mp1[p + 2] - Gp1[p + 1];
                return G0[p + 1] + (0.5f * (fU * dU + fD * dD)) * rcpf(0.5f * (fU + fD) + EPSF);
            };
            auto corners = [&](int p) -> float {
                float dUL = Mm1[p + 1] - Gm1[p],     dUR = Mm1[p + 3] - Gm1[p + 2];
                float dDL = Mp1[p + 1] - Gp1[p],     dDR = Mp1[p + 3] - Gp1[p + 2];
                float num = 0.25f * (fU * (wl(p) * dUL + wr(p) * dUR) + fD * (wl(p) * dDL + wr(p) * dDR));
                float den = 0.25f * ((fU + fD) * (wl(p) + wr(p)));
                return G0[p + 1] + num * rcpf(den + EPSF);
            };
            if ((y & 1) == 0) {
                R[0] = pair_h(0);  Bv[0] = pair_v(0);
                R[1] = M0[3];      Bv[1] = corners(1);
                R[2] = pair_h(2);  Bv[2] = pair_v(2);
                R[3] = M0[5];      Bv[3] = corners(3);
            } else {
                R[0] = corners(0); Bv[0] = M0[2];
                R[1] = pair_v(1);  Bv[1] = pair_h(1);
                R[2] = corners(2); Bv[2] = M0[4];
                R[3] = pair_v(3);  Bv[3] = pair_h(3);
            }
        }

        float* prow = obase + (size_t)y * WW;
        ntstore4(prow,             R[0], R[1], R[2], R[3]);
        ntstore4(prow + plane,     g0, g1, g2, g3);
        ntstore4(prow + 2 * plane, Bv[0], Bv[1], Bv[2], Bv[3]);

        #pragma unroll
        for (int j = 0; j < 8; ++j) { Mm1[j] = M0[j]; M0[j] = Mp1[j]; Mp1[j] = Mp2[j]; }
        #pragma unroll
        for (int j = 0; j < 6; ++j) { Gm1[j] = G0[j]; G0[j] = Gp1[j]; }
    }
}

extern "C" void kernel_launch(void* const* d_in, const int* in_sizes, int n_in,
                              void* d_out, int out_size, void* d_ws, size_t ws_size,
                              hipStream_t stream) {
    const float* mos = (const float*)d_in[0];
    const float* gf  = (const float*)d_in[1];
    const float* df  = (const float*)d_in[2];
    float* o = (float*)d_out;
    int B = in_sizes[0] / (HH * WW);
    dim3 grid(1, HH / ROWS, B);
    demosaick<<<grid, dim3(256, 1, 1), 0, stream>>>(mos, gf, df, o);
}